// Round 3
// baseline (191.231 us; speedup 1.0000x reference)
//
#include <hip/hip_runtime.h>
#include <hip/hip_bf16.h>

#define NN 4096
#define IN_F 512
#define HALF 256
#define FF 64
#define ALPHA 0.2f
#define EPSV 1e-5f
#define CAP2 1024
#define H1B 1024   // hop-1 blocks (4 rows each, one per wave)

typedef unsigned long long u64;
typedef unsigned int u32;

__device__ __forceinline__ float lrelu(float x){ return x > 0.f ? x : ALPHA * x; }

__device__ __forceinline__ float wave_fmax(float v){
    #pragma unroll
    for (int off = 32; off; off >>= 1) v = fmaxf(v, __shfl_xor(v, off, 64));
    return v;
}
__device__ __forceinline__ float wave_fsum(float v){
    #pragma unroll
    for (int off = 32; off; off >>= 1) v += __shfl_xor(v, off, 64);
    return v;
}

// Build compacted index list from one u64 word per lane (wave-wide).
// Indices only — no dependent gathers inside the serial bit loop.
__device__ __forceinline__ int build_idx(u64 bits, int lane, int cap, int* __restrict__ nbr){
    int pc = __popcll(bits);
    int scan = pc;
    #pragma unroll
    for (int off = 1; off < 64; off <<= 1) {
        int v = __shfl_up(scan, off, 64);
        if (lane >= off) scan += v;
    }
    int total = __shfl(scan, 63, 64);
    int pos = scan - pc;
    while (bits) {
        int b = __builtin_ctzll(bits);
        bits &= bits - 1;
        if (pos < cap) nbr[pos] = (lane << 6) | b;
        ++pos;
    }
    return total;
}

// ---------------- Kernel 1: bit-pack adjacency rows ----------------
__global__ __launch_bounds__(256) void pack_kernel(const float* __restrict__ adj,
                                                   u64* __restrict__ packA) {
    int i = blockIdx.x;
    int tid = threadIdx.x;
    int wave = tid >> 6, lane = tid & 63;
    const float* row = adj + (size_t)i * NN;
    #pragma unroll
    for (int t = 0; t < NN / 256; ++t) {
        int col = t * 256 + tid;
        u64 m = __ballot(row[col] > 0.f);
        if (lane == 0) packA[(size_t)i * 64 + t * 4 + wave] = m;
    }
}

// ---------------- Kernel 2: Wh GEMV, 4 rows/block with W register reuse ----------------
__global__ __launch_bounds__(128) void wh_kernel(const float* __restrict__ h,
                                                 const float* __restrict__ W1,
                                                 const float* __restrict__ W2,
                                                 const float* __restrict__ a,
                                                 float* __restrict__ Wh1,
                                                 float* __restrict__ Wh2,
                                                 float* __restrict__ s11,
                                                 float* __restrict__ s12,
                                                 float* __restrict__ s21,
                                                 float* __restrict__ s22) {
    __shared__ float hs[4 * IN_F];
    int r0 = blockIdx.x * 4;
    int tid = threadIdx.x;
    const float4* hsrc = (const float4*)(h + (size_t)r0 * IN_F);
    float4* hdst = (float4*)hs;
    #pragma unroll
    for (int t = 0; t < 4; ++t) hdst[tid + 128 * t] = hsrc[tid + 128 * t];
    __syncthreads();

    int wave = tid >> 6, f = tid & 63;
    const float* W = wave ? W2 : W1;
    const float* hw = hs + wave * HALF;
    float acc0 = 0.f, acc1 = 0.f, acc2 = 0.f, acc3 = 0.f;
    #pragma unroll 4
    for (int k = 0; k < HALF; ++k) {
        float w = W[k * FF + f];
        acc0 += hw[k] * w;
        acc1 += hw[IN_F + k] * w;
        acc2 += hw[2 * IN_F + k] * w;
        acc3 += hw[3 * IN_F + k] * w;
    }
    float* Wh = wave ? Wh2 : Wh1;
    Wh[(size_t)(r0 + 0) * FF + f] = acc0;
    Wh[(size_t)(r0 + 1) * FF + f] = acc1;
    Wh[(size_t)(r0 + 2) * FF + f] = acc2;
    Wh[(size_t)(r0 + 3) * FF + f] = acc3;

    float a1 = a[f], a2 = a[64 + f];
    #pragma unroll
    for (int r = 0; r < 4; ++r) {
        float acc = (r == 0) ? acc0 : (r == 1) ? acc1 : (r == 2) ? acc2 : acc3;
        float v1 = acc * a1, v2 = acc * a2;
        #pragma unroll
        for (int off = 32; off; off >>= 1) {
            v1 += __shfl_down(v1, off, 64);
            v2 += __shfl_down(v2, off, 64);
        }
        if (f == 0) {
            if (wave == 0) { s11[r0 + r] = v1; s12[r0 + r] = v2; }
            else           { s21[r0 + r] = v1; s22[r0 + r] = v2; }
        }
    }
}

// ---------------- Kernel 3: fused attention ----------------
// blocks [0, H1B): hop-1, 4 rows each (one per wave, wave-local softmax)
// blocks [H1B, H1B+NN): hop-2, one row each
__global__ __launch_bounds__(256) void attn_kernel(const u64* __restrict__ packA,
                                                   const float* __restrict__ Wh1,
                                                   const float* __restrict__ Wh2,
                                                   const float* __restrict__ s11,
                                                   const float* __restrict__ s12,
                                                   const float* __restrict__ s21,
                                                   const float* __restrict__ s22,
                                                   float* __restrict__ hp) {
    __shared__ int   nbr[CAP2];
    __shared__ float ev[CAP2];
    __shared__ u64   maskw[256];
    __shared__ float red[8];
    __shared__ float partial[1024];
    __shared__ int   scnt;

    int bid = blockIdx.x;
    int tid = threadIdx.x;
    int w = tid >> 6, lane = tid & 63;

    if (bid < H1B) {
        // ---------- hop-1: wave w handles row 4*bid + w ----------
        int row = bid * 4 + w;
        int*   mynbr  = nbr + w * 256;
        float* myev   = ev + w * 256;
        float* mypart = partial + w * 256;

        int total = build_idx(packA[(size_t)row * 64 + lane], lane, 256, mynbr);
        int c = min(total, 256);
        __syncthreads();                         // mynbr visible cross-lane

        float Z;
        if (c > 0) {
            float s11i = s11[row];
            float lm = -3.4e38f;
            for (int n = lane; n < c; n += 64) {
                float e = lrelu(s11i + s12[mynbr[n]]);
                myev[n] = e;
                lm = fmaxf(lm, e);
            }
            float m = wave_fmax(lm);
            float ls = 0.f;
            for (int n = lane; n < c; n += 64) {
                float p = __expf(myev[n] - m);
                myev[n] = p;
                ls += p;
            }
            Z = wave_fsum(ls);
        } else {
            Z = (float)NN;
        }
        __syncthreads();                         // myev visible cross-lane

        int g = lane >> 4, fq = (lane & 15) << 2;
        float ax = 0.f, ay = 0.f, az = 0.f, aw = 0.f;
        if (c > 0) {
            #pragma unroll 4
            for (int n = g; n < c; n += 4) {
                float wg = myev[n];
                const float4 v = *reinterpret_cast<const float4*>(&Wh1[(size_t)mynbr[n] * FF + fq]);
                ax += wg * v.x; ay += wg * v.y; az += wg * v.z; aw += wg * v.w;
            }
        } else {
            #pragma unroll 4
            for (int n = g; n < NN; n += 4) {
                const float4 v = *reinterpret_cast<const float4*>(&Wh1[(size_t)n * FF + fq]);
                ax += v.x; ay += v.y; az += v.z; aw += v.w;
            }
        }
        *reinterpret_cast<float4*>(&mypart[g * 64 + fq]) = make_float4(ax, ay, az, aw);
        __syncthreads();
        float s = mypart[lane] + mypart[64 + lane] + mypart[128 + lane] + mypart[192 + lane];
        hp[(size_t)row * 128 + lane] = s / Z;
    } else {
        // ---------- hop-2: one row per block ----------
        int i = bid - H1B;
        if (w == 0) {
            int t1 = build_idx(packA[(size_t)i * 64 + lane], lane, CAP2, nbr);
            if (lane == 0) scnt = t1;
        }
        __syncthreads();
        int c1 = min(scnt, CAP2);

        u64 m = 0;
        for (int n = w; n < c1; n += 4)
            m |= packA[(size_t)nbr[n] * 64 + lane];
        maskw[w * 64 + lane] = m;
        __syncthreads();

        if (w == 0) {
            u64 word = maskw[lane] | maskw[64 + lane] | maskw[128 + lane] | maskw[192 + lane];
            if (lane == (i >> 6)) word &= ~(1ull << (i & 63));   // zero adj2 diagonal
            int t2 = build_idx(word, lane, CAP2, nbr);
            if (lane == 0) scnt = t2;
        }
        __syncthreads();
        int c2 = min(scnt, CAP2);

        float Z;
        if (c2 > 0) {
            float s21i = s21[i];
            float lm = -3.4e38f;
            for (int n = tid; n < c2; n += 256) {
                float e = lrelu(s21i + s22[nbr[n]]);
                ev[n] = e;
                lm = fmaxf(lm, e);
            }
            lm = wave_fmax(lm);
            if (lane == 0) red[w] = lm;
            __syncthreads();
            float mx = fmaxf(fmaxf(red[0], red[1]), fmaxf(red[2], red[3]));
            float ls = 0.f;
            for (int n = tid; n < c2; n += 256) {
                float p = __expf(ev[n] - mx);
                ev[n] = p;
                ls += p;
            }
            ls = wave_fsum(ls);
            if (lane == 0) red[4 + w] = ls;
            __syncthreads();
            Z = red[4] + red[5] + red[6] + red[7];
        } else {
            Z = (float)NN;
        }

        int g = tid >> 4, fq = (tid & 15) << 2;
        float ax = 0.f, ay = 0.f, az = 0.f, aw = 0.f;
        if (c2 > 0) {
            #pragma unroll 4
            for (int n = g; n < c2; n += 16) {
                float wg = ev[n];
                const float4 v = *reinterpret_cast<const float4*>(&Wh2[(size_t)nbr[n] * FF + fq]);
                ax += wg * v.x; ay += wg * v.y; az += wg * v.z; aw += wg * v.w;
            }
        } else {
            #pragma unroll 4
            for (int n = g; n < NN; n += 16) {
                const float4 v = *reinterpret_cast<const float4*>(&Wh2[(size_t)n * FF + fq]);
                ax += v.x; ay += v.y; az += v.z; aw += v.w;
            }
        }
        *reinterpret_cast<float4*>(&partial[tid << 2]) = make_float4(ax, ay, az, aw);
        __syncthreads();
        if (tid < 64) {
            float s = 0.f;
            #pragma unroll
            for (int g2 = 0; g2 < 16; ++g2) s += partial[g2 * 64 + tid];
            hp[(size_t)i * 128 + 64 + tid] = s / Z;
        }
    }
}

// ---------------- Kernel 4: per-block column partials (NO global atomics) ----------------
__global__ __launch_bounds__(256) void stats_kernel(const float* __restrict__ hp,
                                                    float* __restrict__ ps,
                                                    float* __restrict__ pq) {
    __shared__ float ls[128], lq[128];
    int tid = threadIdx.x;
    if (tid < 128) { ls[tid] = 0.f; lq[tid] = 0.f; }
    __syncthreads();
    float s0 = 0, s1 = 0, s2 = 0, s3 = 0, q0 = 0, q1 = 0, q2 = 0, q3 = 0;
    const float4* hp4 = (const float4*)hp;
    for (size_t idx = (size_t)blockIdx.x * 256 + tid; idx < (size_t)NN * 32;
         idx += (size_t)gridDim.x * 256) {
        float4 v = hp4[idx];
        s0 += v.x; q0 += v.x * v.x;
        s1 += v.y; q1 += v.y * v.y;
        s2 += v.z; q2 += v.z * v.z;
        s3 += v.w; q3 += v.w * v.w;
    }
    int cb = (tid & 31) << 2;
    atomicAdd(&ls[cb + 0], s0); atomicAdd(&lq[cb + 0], q0);
    atomicAdd(&ls[cb + 1], s1); atomicAdd(&lq[cb + 1], q1);
    atomicAdd(&ls[cb + 2], s2); atomicAdd(&lq[cb + 2], q2);
    atomicAdd(&ls[cb + 3], s3); atomicAdd(&lq[cb + 3], q3);
    __syncthreads();
    if (tid < 128) {
        ps[(size_t)blockIdx.x * 128 + tid] = ls[tid];
        pq[(size_t)blockIdx.x * 128 + tid] = lq[tid];
    }
}

// ---------------- Kernel 4b: finalize column stats (1 block) ----------------
__global__ __launch_bounds__(256) void finalize_kernel(const float* __restrict__ ps,
                                                       const float* __restrict__ pq,
                                                       float* __restrict__ colsum,
                                                       float* __restrict__ colsq) {
    int tid = threadIdx.x;
    const float* src = (tid < 128) ? ps : pq;
    int c = tid & 127;
    float s = 0.f;
    #pragma unroll 8
    for (int b = 0; b < 256; ++b) s += src[(size_t)b * 128 + c];
    if (tid < 128) colsum[c] = s;
    else           colsq[c]  = s;
}

// ---------------- Kernel 5: batchnorm + lrelu, float4 in place ----------------
__global__ __launch_bounds__(256) void norm_kernel(float* __restrict__ hp,
                                                   const float* __restrict__ colsum,
                                                   const float* __restrict__ colsq,
                                                   const float* __restrict__ gamma,
                                                   const float* __restrict__ beta) {
    size_t idx = (size_t)blockIdx.x * 256 + threadIdx.x;
    if (idx >= (size_t)NN * 32) return;
    int cb = (int)((idx << 2) & 127);
    float4 v = ((const float4*)hp)[idx];
    float r[4] = {v.x, v.y, v.z, v.w};
    #pragma unroll
    for (int t = 0; t < 4; ++t) {
        int c = cb + t;
        float mean = colsum[c] * (1.f / NN);
        float var = colsq[c] * (1.f / NN) - mean * mean;
        float inv = rsqrtf(var + EPSV);
        r[t] = lrelu((r[t] - mean) * inv * gamma[c] + beta[c]);
    }
    ((float4*)hp)[idx] = make_float4(r[0], r[1], r[2], r[3]);
}

extern "C" void kernel_launch(void* const* d_in, const int* in_sizes, int n_in,
                              void* d_out, int out_size, void* d_ws, size_t ws_size,
                              hipStream_t stream) {
    const float* h     = (const float*)d_in[0];
    const float* adj   = (const float*)d_in[1];
    const float* W1    = (const float*)d_in[2];
    const float* W2    = (const float*)d_in[3];
    const float* a     = (const float*)d_in[4];
    const float* gamma = (const float*)d_in[5];
    const float* beta  = (const float*)d_in[6];
    float* hp = (float*)d_out;   // [4096, 128]

    u64* packA  = (u64*)d_ws;                         // 2 MB
    float* Wh1  = (float*)(packA + (size_t)NN * 64);  // 1 MB
    float* Wh2  = Wh1 + (size_t)NN * FF;              // 1 MB
    float* s11  = Wh2 + (size_t)NN * FF;
    float* s12  = s11 + NN;
    float* s21  = s12 + NN;
    float* s22  = s21 + NN;
    float* ps   = s22 + NN;                           // 256*128 floats
    float* pq   = ps + 256 * 128;                     // 256*128 floats
    float* colsum = pq + 256 * 128;                   // 128
    float* colsq  = colsum + 128;                     // 128

    pack_kernel<<<NN, 256, 0, stream>>>(adj, packA);
    wh_kernel<<<NN / 4, 128, 0, stream>>>(h, W1, W2, a, Wh1, Wh2, s11, s12, s21, s22);
    attn_kernel<<<H1B + NN, 256, 0, stream>>>(packA, Wh1, Wh2, s11, s12, s21, s22, hp);
    stats_kernel<<<256, 256, 0, stream>>>(hp, ps, pq);
    finalize_kernel<<<1, 256, 0, stream>>>(ps, pq, colsum, colsq);
    norm_kernel<<<(NN * 32 + 255) / 256, 256, 0, stream>>>(hp, colsum, colsq, gamma, beta);
}

// Round 4
// 179.176 us; speedup vs baseline: 1.0673x; 1.0673x over previous
//
#include <hip/hip_runtime.h>
#include <hip/hip_bf16.h>

#define NN 4096
#define IN_F 512
#define HALF 256
#define FF 64
#define ALPHA 0.2f
#define EPSV 1e-5f
#define CAP1 256
#define CAP2 1024

typedef unsigned long long u64;
typedef unsigned int u32;

__device__ __forceinline__ float lrelu(float x){ return x > 0.f ? x : ALPHA * x; }

__device__ __forceinline__ float wave_fmax(float v){
    #pragma unroll
    for (int off = 32; off; off >>= 1) v = fmaxf(v, __shfl_xor(v, off, 64));
    return v;
}
__device__ __forceinline__ float wave_fsum(float v){
    #pragma unroll
    for (int off = 32; off; off >>= 1) v += __shfl_xor(v, off, 64);
    return v;
}

// Wave-wide compaction of set bits (one u64 word per lane) into an index list.
__device__ __forceinline__ int build_idx(u64 bits, int lane, int cap, int* __restrict__ nbr){
    int pc = __popcll(bits);
    int scan = pc;
    #pragma unroll
    for (int off = 1; off < 64; off <<= 1) {
        int v = __shfl_up(scan, off, 64);
        if (lane >= off) scan += v;
    }
    int total = __shfl(scan, 63, 64);
    int pos = scan - pc;
    while (bits) {
        int b = __builtin_ctzll(bits);
        bits &= bits - 1;
        if (pos < cap) nbr[pos] = (lane << 6) | b;
        ++pos;
    }
    return total;
}

// ---------------- Kernel 1: bit-pack adjacency rows ----------------
__global__ __launch_bounds__(256) void pack_kernel(const float* __restrict__ adj,
                                                   u64* __restrict__ packA) {
    int i = blockIdx.x;
    int tid = threadIdx.x;
    int wave = tid >> 6, lane = tid & 63;
    const float* row = adj + (size_t)i * NN;
    #pragma unroll
    for (int t = 0; t < NN / 256; ++t) {
        int col = t * 256 + tid;
        u64 m = __ballot(row[col] > 0.f);
        if (lane == 0) packA[(size_t)i * 64 + t * 4 + wave] = m;
    }
}

// ---------------- Kernel 2: Wh GEMV, 4 rows/block ----------------
__global__ __launch_bounds__(128) void wh_kernel(const float* __restrict__ h,
                                                 const float* __restrict__ W1,
                                                 const float* __restrict__ W2,
                                                 const float* __restrict__ a,
                                                 float* __restrict__ Wh1,
                                                 float* __restrict__ Wh2,
                                                 float* __restrict__ s11,
                                                 float* __restrict__ s12,
                                                 float* __restrict__ s21,
                                                 float* __restrict__ s22) {
    __shared__ float hs[4 * IN_F];
    int r0 = blockIdx.x * 4;
    int tid = threadIdx.x;
    const float4* hsrc = (const float4*)(h + (size_t)r0 * IN_F);
    float4* hdst = (float4*)hs;
    #pragma unroll
    for (int t = 0; t < 4; ++t) hdst[tid + 128 * t] = hsrc[tid + 128 * t];
    __syncthreads();

    int wave = tid >> 6, f = tid & 63;
    const float* W = wave ? W2 : W1;
    const float* hw = hs + wave * HALF;
    float acc0 = 0.f, acc1 = 0.f, acc2 = 0.f, acc3 = 0.f;
    #pragma unroll 4
    for (int k = 0; k < HALF; ++k) {
        float w = W[k * FF + f];
        acc0 += hw[k] * w;
        acc1 += hw[IN_F + k] * w;
        acc2 += hw[2 * IN_F + k] * w;
        acc3 += hw[3 * IN_F + k] * w;
    }
    float* Wh = wave ? Wh2 : Wh1;
    Wh[(size_t)(r0 + 0) * FF + f] = acc0;
    Wh[(size_t)(r0 + 1) * FF + f] = acc1;
    Wh[(size_t)(r0 + 2) * FF + f] = acc2;
    Wh[(size_t)(r0 + 3) * FF + f] = acc3;

    float a1 = a[f], a2 = a[64 + f];
    #pragma unroll
    for (int r = 0; r < 4; ++r) {
        float acc = (r == 0) ? acc0 : (r == 1) ? acc1 : (r == 2) ? acc2 : acc3;
        float v1 = acc * a1, v2 = acc * a2;
        #pragma unroll
        for (int off = 32; off; off >>= 1) {
            v1 += __shfl_down(v1, off, 64);
            v2 += __shfl_down(v2, off, 64);
        }
        if (f == 0) {
            if (wave == 0) { s11[r0 + r] = v1; s12[r0 + r] = v2; }
            else           { s21[r0 + r] = v1; s22[r0 + r] = v2; }
        }
    }
}

// ---------------- Kernel 3: fused attention, BOTH hops, one block per row ----------------
__global__ __launch_bounds__(256) void attn_kernel(const u64* __restrict__ packA,
                                                   const float* __restrict__ Wh1,
                                                   const float* __restrict__ Wh2,
                                                   const float* __restrict__ s11,
                                                   const float* __restrict__ s12,
                                                   const float* __restrict__ s21,
                                                   const float* __restrict__ s22,
                                                   float* __restrict__ hp) {
    __shared__ int   nbr1[CAP1];
    __shared__ float ev1[CAP1];
    __shared__ int   nbr2[CAP2];
    __shared__ float ev2[CAP2];
    __shared__ u64   maskw[3 * 64];
    __shared__ float red[8];
    __shared__ float partial[1024];
    __shared__ int   scnt1, scnt2;

    int i = blockIdx.x;
    int tid = threadIdx.x;
    int w = tid >> 6, lane = tid & 63;

    // ---- build 1-hop list once (wave 0) ----
    if (w == 0) {
        int t1 = build_idx(packA[(size_t)i * 64 + lane], lane, CAP1, nbr1);
        if (lane == 0) scnt1 = t1;
    }
    __syncthreads();
    int c1 = min(scnt1, CAP1);

    if (c1 > 0) {
        if (w == 0) {
            // ---- hop-1 entirely within wave 0 (wave-local LDS, no block barriers) ----
            float s11i = s11[i];
            float lm = -3.4e38f;
            for (int n = lane; n < c1; n += 64) {
                float e = lrelu(s11i + s12[nbr1[n]]);
                ev1[n] = e;
                lm = fmaxf(lm, e);
            }
            float m = wave_fmax(lm);
            float ls = 0.f;
            for (int n = lane; n < c1; n += 64) {
                float p = __expf(ev1[n] - m);
                ev1[n] = p;
                ls += p;
            }
            float Z = wave_fsum(ls);
            float acc = 0.f;
            #pragma unroll 4
            for (int n = 0; n < c1; ++n)
                acc += ev1[n] * Wh1[(size_t)nbr1[n] * FF + lane];
            hp[(size_t)i * 128 + lane] = acc / Z;
        } else {
            // ---- waves 1-3: 2-hop mask OR (L2 loads overlap wave-0 compute) ----
            u64 m = 0;
            for (int n = w - 1; n < c1; n += 3)
                m |= packA[(size_t)nbr1[n] * 64 + lane];
            maskw[(w - 1) * 64 + lane] = m;
        }
    } else {
        // degenerate row: uniform attention over all NN (block-uniform branch)
        int g = tid >> 4, fq = (tid & 15) << 2;
        float ax = 0.f, ay = 0.f, az = 0.f, aw = 0.f;
        for (int n = g; n < NN; n += 16) {
            const float4 v = *reinterpret_cast<const float4*>(&Wh1[(size_t)n * FF + fq]);
            ax += v.x; ay += v.y; az += v.z; aw += v.w;
        }
        *reinterpret_cast<float4*>(&partial[tid << 2]) = make_float4(ax, ay, az, aw);
        if (w) maskw[(w - 1) * 64 + lane] = 0;
        __syncthreads();
        if (tid < 64) {
            float s = 0.f;
            #pragma unroll
            for (int g2 = 0; g2 < 16; ++g2) s += partial[g2 * 64 + tid];
            hp[(size_t)i * 128 + tid] = s / (float)NN;
        }
    }
    __syncthreads();

    // ---- combine mask, build 2-hop list (wave 0) ----
    if (w == 0) {
        u64 word = maskw[lane] | maskw[64 + lane] | maskw[128 + lane];
        if (lane == (i >> 6)) word &= ~(1ull << (i & 63));   // zero adj2 diagonal
        int t2 = build_idx(word, lane, CAP2, nbr2);
        if (lane == 0) scnt2 = t2;
    }
    __syncthreads();
    int c2 = min(scnt2, CAP2);

    // ---- hop-2 softmax (all 256 threads) ----
    float Z2;
    if (c2 > 0) {
        float s21i = s21[i];
        float lm = -3.4e38f;
        for (int n = tid; n < c2; n += 256) {
            float e = lrelu(s21i + s22[nbr2[n]]);
            ev2[n] = e;
            lm = fmaxf(lm, e);
        }
        lm = wave_fmax(lm);
        if (lane == 0) red[w] = lm;
        __syncthreads();
        float mx = fmaxf(fmaxf(red[0], red[1]), fmaxf(red[2], red[3]));
        float ls = 0.f;
        for (int n = tid; n < c2; n += 256) {
            float p = __expf(ev2[n] - mx);
            ev2[n] = p;
            ls += p;
        }
        ls = wave_fsum(ls);
        if (lane == 0) red[4 + w] = ls;
        __syncthreads();
        Z2 = red[4] + red[5] + red[6] + red[7];
    } else {
        Z2 = (float)NN;
    }

    // ---- hop-2 gather: 16 row-groups x 16 lanes, float4 ----
    int g = tid >> 4, fq = (tid & 15) << 2;
    float ax = 0.f, ay = 0.f, az = 0.f, aw = 0.f;
    if (c2 > 0) {
        #pragma unroll 4
        for (int n = g; n < c2; n += 16) {
            float wg = ev2[n];
            const float4 v = *reinterpret_cast<const float4*>(&Wh2[(size_t)nbr2[n] * FF + fq]);
            ax += wg * v.x; ay += wg * v.y; az += wg * v.z; aw += wg * v.w;
        }
    } else {
        #pragma unroll 4
        for (int n = g; n < NN; n += 16) {
            const float4 v = *reinterpret_cast<const float4*>(&Wh2[(size_t)n * FF + fq]);
            ax += v.x; ay += v.y; az += v.z; aw += v.w;
        }
    }
    __syncthreads();   // partial[] reuse from degenerate hop-1 path
    *reinterpret_cast<float4*>(&partial[tid << 2]) = make_float4(ax, ay, az, aw);
    __syncthreads();
    if (tid < 64) {
        float s = 0.f;
        #pragma unroll
        for (int g2 = 0; g2 < 16; ++g2) s += partial[g2 * 64 + tid];
        hp[(size_t)i * 128 + 64 + tid] = s / Z2;
    }
}

// ---------------- Kernel 4: per-block column partials ----------------
__global__ __launch_bounds__(256) void stats_kernel(const float* __restrict__ hp,
                                                    float* __restrict__ ps,
                                                    float* __restrict__ pq) {
    __shared__ float ls[128], lq[128];
    int tid = threadIdx.x;
    if (tid < 128) { ls[tid] = 0.f; lq[tid] = 0.f; }
    __syncthreads();
    float s0 = 0, s1 = 0, s2 = 0, s3 = 0, q0 = 0, q1 = 0, q2 = 0, q3 = 0;
    const float4* hp4 = (const float4*)hp;
    for (size_t idx = (size_t)blockIdx.x * 256 + tid; idx < (size_t)NN * 32;
         idx += (size_t)gridDim.x * 256) {
        float4 v = hp4[idx];
        s0 += v.x; q0 += v.x * v.x;
        s1 += v.y; q1 += v.y * v.y;
        s2 += v.z; q2 += v.z * v.z;
        s3 += v.w; q3 += v.w * v.w;
    }
    int cb = (tid & 31) << 2;
    atomicAdd(&ls[cb + 0], s0); atomicAdd(&lq[cb + 0], q0);
    atomicAdd(&ls[cb + 1], s1); atomicAdd(&lq[cb + 1], q1);
    atomicAdd(&ls[cb + 2], s2); atomicAdd(&lq[cb + 2], q2);
    atomicAdd(&ls[cb + 3], s3); atomicAdd(&lq[cb + 3], q3);
    __syncthreads();
    if (tid < 128) {
        ps[(size_t)blockIdx.x * 128 + tid] = ls[tid];
        pq[(size_t)blockIdx.x * 128 + tid] = lq[tid];
    }
}

// ---------------- Kernel 4b: finalize column stats ----------------
__global__ __launch_bounds__(256) void finalize_kernel(const float* __restrict__ ps,
                                                       const float* __restrict__ pq,
                                                       float* __restrict__ colsum,
                                                       float* __restrict__ colsq) {
    int tid = threadIdx.x;
    const float* src = (tid < 128) ? ps : pq;
    int c = tid & 127;
    float s = 0.f;
    #pragma unroll 8
    for (int b = 0; b < 256; ++b) s += src[(size_t)b * 128 + c];
    if (tid < 128) colsum[c] = s;
    else           colsq[c]  = s;
}

// ---------------- Kernel 5: batchnorm + lrelu ----------------
__global__ __launch_bounds__(256) void norm_kernel(float* __restrict__ hp,
                                                   const float* __restrict__ colsum,
                                                   const float* __restrict__ colsq,
                                                   const float* __restrict__ gamma,
                                                   const float* __restrict__ beta) {
    size_t idx = (size_t)blockIdx.x * 256 + threadIdx.x;
    if (idx >= (size_t)NN * 32) return;
    int cb = (int)((idx << 2) & 127);
    float4 v = ((const float4*)hp)[idx];
    float r[4] = {v.x, v.y, v.z, v.w};
    #pragma unroll
    for (int t = 0; t < 4; ++t) {
        int c = cb + t;
        float mean = colsum[c] * (1.f / NN);
        float var = colsq[c] * (1.f / NN) - mean * mean;
        float inv = rsqrtf(var + EPSV);
        r[t] = lrelu((r[t] - mean) * inv * gamma[c] + beta[c]);
    }
    ((float4*)hp)[idx] = make_float4(r[0], r[1], r[2], r[3]);
}

extern "C" void kernel_launch(void* const* d_in, const int* in_sizes, int n_in,
                              void* d_out, int out_size, void* d_ws, size_t ws_size,
                              hipStream_t stream) {
    const float* h     = (const float*)d_in[0];
    const float* adj   = (const float*)d_in[1];
    const float* W1    = (const float*)d_in[2];
    const float* W2    = (const float*)d_in[3];
    const float* a     = (const float*)d_in[4];
    const float* gamma = (const float*)d_in[5];
    const float* beta  = (const float*)d_in[6];
    float* hp = (float*)d_out;   // [4096, 128]

    u64* packA  = (u64*)d_ws;                         // 2 MB
    float* Wh1  = (float*)(packA + (size_t)NN * 64);  // 1 MB
    float* Wh2  = Wh1 + (size_t)NN * FF;              // 1 MB
    float* s11  = Wh2 + (size_t)NN * FF;
    float* s12  = s11 + NN;
    float* s21  = s12 + NN;
    float* s22  = s21 + NN;
    float* ps   = s22 + NN;                           // 256*128
    float* pq   = ps + 256 * 128;                     // 256*128
    float* colsum = pq + 256 * 128;                   // 128
    float* colsq  = colsum + 128;                     // 128

    pack_kernel<<<NN, 256, 0, stream>>>(adj, packA);
    wh_kernel<<<NN / 4, 128, 0, stream>>>(h, W1, W2, a, Wh1, Wh2, s11, s12, s21, s22);
    attn_kernel<<<NN, 256, 0, stream>>>(packA, Wh1, Wh2, s11, s12, s21, s22, hp);
    stats_kernel<<<256, 256, 0, stream>>>(hp, ps, pq);
    finalize_kernel<<<1, 256, 0, stream>>>(ps, pq, colsum, colsq);
    norm_kernel<<<(NN * 32 + 255) / 256, 256, 0, stream>>>(hp, colsum, colsq, gamma, beta);
}